// Round 5
// baseline (299.192 us; speedup 1.0000x reference)
//
#include <hip/hip_runtime.h>

#define SEQ  2048
#define DIM  1024
#define NTOK 8192   // 4*SEQ
#define NQKV 3072
#define BK   32

typedef __attribute__((ext_vector_type(8)))  __bf16 bf16x8;
typedef __attribute__((ext_vector_type(16))) float  f32x16;

__device__ __forceinline__ unsigned short f2bf(float f) {
    unsigned int u = __float_as_uint(f);
    u += 0x7fffu + ((u >> 16) & 1u);          // round-to-nearest-even
    return (unsigned short)(u >> 16);
}

__device__ __forceinline__ float bfu2f(unsigned int lo16) {
    return __uint_as_float(lo16 << 16);
}

__device__ __forceinline__ void load_lds_128(const unsigned short* g, unsigned short* l) {
    __builtin_amdgcn_global_load_lds(
        (const __attribute__((address_space(1))) void*)g,
        (__attribute__((address_space(3))) void*)l, 16, 0, 0);
}

// ---------------------------------------------------------------------------
// NT GEMM, bf16 MFMA 32x32x16, 128x128 block, BK=32, 4 waves (2x2 of 64x64).
// DOUBLE-BUFFERED LDS, ONE barrier per K-iter: loads for iter k+1 are issued
// before the MFMA work of iter k, so the vmcnt(0) drain at the barrier is
// hidden behind compute instead of exposed (R4 post-mortem: ~80% of each
// block-iter was exposed drain latency).
// MODE 0: fused QKV epilogue (q,k bf16 + bias; v transposed into vt + bias)
// MODE 1: fp32 C = acc * inv_rs[row]   (normalized P.V output)
// MODE 2: bf16 C = exp(acc * alpha)    (unnormalized softmax numerator)
// ---------------------------------------------------------------------------
template <int MODE>
__global__ __launch_bounds__(256)
void gemm_bt(const unsigned short* __restrict__ A, const unsigned short* __restrict__ B,
             void* __restrict__ Cv,
             const float* __restrict__ b0, const float* __restrict__ b1,
             const float* __restrict__ b2, unsigned short* __restrict__ vt,
             const float* __restrict__ inv_rs,
             int K, int lda, int ldb, int ldc,
             long sA, long sB, long sC, float alpha)
{
    __shared__ unsigned short As[2][128 * BK];   // 2 x 8 KB
    __shared__ unsigned short Bs[2][128 * BK];   // 2 x 8 KB

    const int tid  = threadIdx.x;
    const int wave = tid >> 6;
    const int lane = tid & 63;
    const int l31  = lane & 31;
    const int half = lane >> 5;

    const int m0 = blockIdx.x * 128;
    const int n0 = blockIdx.y * 128;
    const int z  = blockIdx.z;
    A += (long)z * sA;
    B += (long)z * sB;

    const int wm = (wave >> 1) * 64;
    const int wn = (wave & 1) * 64;

    f32x16 acc[2][2] = {};

    // staging map: chunk tid -> tile row tid>>2, 16B slot tid&3 (no swizzle;
    // R3/R4 showed SQ_LDS_BANK_CONFLICT is the structural 8-wrap count)
    const int r0 = tid >> 2;
    const int c0 = (tid & 3) << 3;
    const unsigned short* Ag0 = A + (long)(m0 + r0) * lda + c0;
    const unsigned short* Ag1 = A + (long)(m0 + 64 + r0) * lda + c0;
    const unsigned short* Bg0 = B + (long)(n0 + r0) * ldb + c0;
    const unsigned short* Bg1 = B + (long)(n0 + 64 + r0) * ldb + c0;
    const int lo0 = tid * 8;            // lane-contiguous LDS dest (wave base + lane*16B)
    const int lo1 = (tid + 256) * 8;

    // fragment LDS offsets (lane-constant): A[m=l31+i*32][k=h*16+half*8+j]
    int Afo[2][2], Bfo[2][2];
#pragma unroll
    for (int i = 0; i < 2; ++i)
#pragma unroll
        for (int h = 0; h < 2; ++h) {
            Afo[i][h] = (wm + i * 32 + l31) * BK + h * 16 + half * 8;
            Bfo[i][h] = (wn + i * 32 + l31) * BK + h * 16 + half * 8;
        }

    // prologue: stage k0=0 into buffer 0
    load_lds_128(Ag0, &As[0][lo0]);
    load_lds_128(Ag1, &As[0][lo1]);
    load_lds_128(Bg0, &Bs[0][lo0]);
    load_lds_128(Bg1, &Bs[0][lo1]);
    __syncthreads();

#pragma unroll 2
    for (int k0 = 0; k0 < K; k0 += BK) {
        const int cur = (k0 / BK) & 1;
        const int nxt = cur ^ 1;
        if (k0 + BK < K) {                    // prefetch next K-slab
            load_lds_128(Ag0 + k0 + BK, &As[nxt][lo0]);
            load_lds_128(Ag1 + k0 + BK, &As[nxt][lo1]);
            load_lds_128(Bg0 + k0 + BK, &Bs[nxt][lo0]);
            load_lds_128(Bg1 + k0 + BK, &Bs[nxt][lo1]);
        }
        bf16x8 a[2][2], b[2][2];
#pragma unroll
        for (int i = 0; i < 2; ++i)
#pragma unroll
            for (int h = 0; h < 2; ++h) {
                a[i][h] = *(const bf16x8*)&As[cur][Afo[i][h]];
                b[i][h] = *(const bf16x8*)&Bs[cur][Bfo[i][h]];
            }
#pragma unroll
        for (int h = 0; h < 2; ++h)
#pragma unroll
            for (int i = 0; i < 2; ++i)
#pragma unroll
                for (int j = 0; j < 2; ++j)
                    acc[i][j] = __builtin_amdgcn_mfma_f32_32x32x16_bf16(
                        a[i][h], b[j][h], acc[i][j], 0, 0, 0);
        __syncthreads();   // drains prefetch (hidden behind MFMA) + guards reuse
    }

    // C/D: col = lane&31, row = (reg&3) + 8*(reg>>2) + 4*(lane>>5)  [m74/m101]
    if (MODE == 0) {
        if (n0 >= 2048) {
            // V columns -> vt[b][d][m] (+bias), packed 4-m ushort4 stores
#pragma unroll
            for (int j = 0; j < 2; ++j) {
                const int d = n0 - 2048 + wn + j * 32 + l31;
                const float bias = b2[d];
#pragma unroll
                for (int i = 0; i < 2; ++i) {
                    const int mbase = m0 + wm + i * 32 + 4 * half;
#pragma unroll
                    for (int rq = 0; rq < 4; ++rq) {
                        const int rowi = mbase + 8 * rq;
                        const int bb = rowi >> 11;
                        const int mm = rowi & 2047;
                        ushort4 u;
                        u.x = f2bf(acc[i][j][rq * 4 + 0] + bias);
                        u.y = f2bf(acc[i][j][rq * 4 + 1] + bias);
                        u.z = f2bf(acc[i][j][rq * 4 + 2] + bias);
                        u.w = f2bf(acc[i][j][rq * 4 + 3] + bias);
                        *(ushort4*)(vt + ((long)bb * DIM + d) * SEQ + mm) = u;
                    }
                }
            }
        } else {
            unsigned short* C16 = (unsigned short*)Cv;
#pragma unroll
            for (int j = 0; j < 2; ++j) {
                const int col = n0 + wn + j * 32 + l31;
                const float* bp = (col >> 10) ? b1 : b0;
                const float bias = bp[col & 1023];
#pragma unroll
                for (int i = 0; i < 2; ++i)
#pragma unroll
                    for (int r = 0; r < 16; ++r) {
                        const int rowi = m0 + wm + i * 32 + (r & 3) + 8 * (r >> 2) + 4 * half;
                        C16[(long)rowi * ldc + col] = f2bf(acc[i][j][r] + bias);
                    }
            }
        }
    } else if (MODE == 1) {
        float* C = (float*)Cv + (long)z * sC;
        const float* ir = inv_rs + (long)z * SEQ;
#pragma unroll
        for (int i = 0; i < 2; ++i) {
            const int rbase = m0 + wm + i * 32 + 4 * half;
#pragma unroll
            for (int rq = 0; rq < 4; ++rq) {
                const float4 inv4 = *(const float4*)(ir + rbase + 8 * rq);
#pragma unroll
                for (int j = 0; j < 2; ++j) {
                    const int col = n0 + wn + j * 32 + l31;
                    C[(long)(rbase + 8 * rq + 0) * ldc + col] = acc[i][j][rq * 4 + 0] * inv4.x;
                    C[(long)(rbase + 8 * rq + 1) * ldc + col] = acc[i][j][rq * 4 + 1] * inv4.y;
                    C[(long)(rbase + 8 * rq + 2) * ldc + col] = acc[i][j][rq * 4 + 2] * inv4.z;
                    C[(long)(rbase + 8 * rq + 3) * ldc + col] = acc[i][j][rq * 4 + 3] * inv4.w;
                }
            }
        }
    } else {  // MODE 2: P = exp(acc * alpha), bf16, unnormalized
        unsigned short* C16 = (unsigned short*)Cv + (long)z * sC;
#pragma unroll
        for (int j = 0; j < 2; ++j) {
            const int col = n0 + wn + j * 32 + l31;
#pragma unroll
            for (int i = 0; i < 2; ++i)
#pragma unroll
                for (int r = 0; r < 16; ++r) {
                    const int rowi = m0 + wm + i * 32 + (r & 3) + 8 * (r >> 2) + 4 * half;
                    C16[(long)rowi * ldc + col] = f2bf(__expf(acc[i][j][r] * alpha));
                }
        }
    }
}

// ---------------------------------------------------------------------------
// Single launch: convert x (8192x1024) and Wq|Wk|Wv (each 1024x1024) to bf16.
// ---------------------------------------------------------------------------
__global__ __launch_bounds__(256)
void cvt_all(const float* __restrict__ x, const float* __restrict__ Wq,
             const float* __restrict__ Wk, const float* __restrict__ Wv,
             unsigned short* __restrict__ xb, unsigned short* __restrict__ Wb)
{
    const long NX = (long)NTOK * DIM / 4;     // 2M float4 groups
    const long NW = (long)DIM * DIM / 4;      // 256K
    long i = (long)blockIdx.x * 256 + threadIdx.x;
    const float* src;
    unsigned short* dst;
    long j;
    if (i < NX)               { src = x;  dst = xb;               j = i; }
    else if (i < NX + NW)     { src = Wq; dst = Wb;               j = i - NX; }
    else if (i < NX + 2 * NW) { src = Wk; dst = Wb + DIM * DIM;   j = i - NX - NW; }
    else                      { src = Wv; dst = Wb + 2 * DIM * DIM; j = i - NX - 2 * NW; }
    float4 f = ((const float4*)src)[j];
    ushort4 u;
    u.x = f2bf(f.x); u.y = f2bf(f.y); u.z = f2bf(f.z); u.w = f2bf(f.w);
    ((ushort4*)dst)[j] = u;
}

// ---------------------------------------------------------------------------
// inv_rs[row] = 1 / sum(P[row][:]) over 2048 bf16 values. 1 wave per row.
// ---------------------------------------------------------------------------
__global__ __launch_bounds__(256)
void rowsum_inv(const unsigned short* __restrict__ P, float* __restrict__ inv_rs)
{
    const int row  = blockIdx.x * 4 + (threadIdx.x >> 6);
    const int lane = threadIdx.x & 63;
    const unsigned short* pr = P + (long)row * SEQ;

    float s = 0.f;
#pragma unroll
    for (int it = 0; it < 4; ++it) {
        uint4 u = *(const uint4*)(pr + (it * 64 + lane) * 8);
        s += bfu2f(u.x & 0xffffu) + __uint_as_float(u.x & 0xffff0000u);
        s += bfu2f(u.y & 0xffffu) + __uint_as_float(u.y & 0xffff0000u);
        s += bfu2f(u.z & 0xffffu) + __uint_as_float(u.z & 0xffff0000u);
        s += bfu2f(u.w & 0xffffu) + __uint_as_float(u.w & 0xffff0000u);
    }
    for (int off = 32; off > 0; off >>= 1)
        s += __shfl_xor(s, off);
    if (lane == 0) inv_rs[row] = 1.0f / s;
}

// ---------------------------------------------------------------------------
extern "C" void kernel_launch(void* const* d_in, const int* in_sizes, int n_in,
                              void* d_out, int out_size, void* d_ws, size_t ws_size,
                              hipStream_t stream)
{
    const float* x  = (const float*)d_in[0];
    const float* Wq = (const float*)d_in[1];
    const float* bq = (const float*)d_in[2];
    const float* Wk = (const float*)d_in[3];
    const float* bk = (const float*)d_in[4];
    const float* Wv = (const float*)d_in[5];
    const float* bv = (const float*)d_in[6];
    float* out = (float*)d_out;

    // Workspace (>=167.8MB proven R1):
    //  [0,16MB):    xb bf16 [8192][1024]
    //  [16,22MB):   Wb bf16 [3][1024][1024]
    //  [64,112MB):  qkv bf16 [8192][3072]  (V cols never written; vt instead)
    //  [112,128MB): vt  bf16 [4][1024][2048]
    //  [128,160MB): P   bf16 [4][2048][2048]  (unnormalized exp)
    //  [160MB,+32KB): inv_rs fp32 [8192]
    char* ws = (char*)d_ws;
    unsigned short* xb   = (unsigned short*)ws;
    unsigned short* Wb   = (unsigned short*)(ws + 16u * 1024 * 1024);
    unsigned short* qkv  = (unsigned short*)(ws + 64u * 1024 * 1024);
    unsigned short* vt   = (unsigned short*)(ws + 112u * 1024 * 1024);
    unsigned short* P    = (unsigned short*)(ws + 128u * 1024 * 1024);
    float*          irs  = (float*)(ws + 160u * 1024 * 1024);

    const float scale = 0.03125f;   // 1/sqrt(1024)
    dim3 blk(256);

    // 1) converts (single launch)
    cvt_all<<<(NTOK * DIM / 4 + 3 * DIM * DIM / 4) / 256, blk, 0, stream>>>(
        x, Wq, Wk, Wv, xb, Wb);

    // 2) fused QKV projection (V transposed into vt in-epilogue)
    gemm_bt<0><<<dim3(NTOK / 128, NQKV / 128), blk, 0, stream>>>(
        xb, Wb, qkv, bq, bk, bv, vt, nullptr,
        DIM, DIM, DIM, NQKV, 0, 0, 0, 1.0f);

    // 3) P[b] = exp(q[b] . k[b]^T * scale)  (bf16, unnormalized)
    gemm_bt<2><<<dim3(SEQ / 128, SEQ / 128, 4), blk, 0, stream>>>(
        qkv, qkv + 1024, P, nullptr, nullptr, nullptr, nullptr, nullptr,
        DIM, NQKV, NQKV, SEQ,
        (long)SEQ * NQKV, (long)SEQ * NQKV, (long)SEQ * SEQ, scale);

    // 4) inv_rs = 1 / rowsum(P)
    rowsum_inv<<<NTOK / 4, blk, 0, stream>>>(P, irs);

    // 5) out[b] = (P[b] . vt[b]^T) * inv_rs   (fp32)
    gemm_bt<1><<<dim3(SEQ / 128, DIM / 128, 4), blk, 0, stream>>>(
        P, vt, out, nullptr, nullptr, nullptr, nullptr, irs,
        SEQ, SEQ, SEQ, DIM,
        (long)SEQ * SEQ, (long)DIM * SEQ, (long)SEQ * DIM, 1.0f);
}

// Round 6
// 285.937 us; speedup vs baseline: 1.0464x; 1.0464x over previous
//
#include <hip/hip_runtime.h>

#define SEQ  2048
#define DIM  1024
#define NTOK 8192   // 4*SEQ
#define NQKV 3072
#define BK   64

typedef __attribute__((ext_vector_type(8)))  __bf16 bf16x8;
typedef __attribute__((ext_vector_type(16))) float  f32x16;

__device__ __forceinline__ unsigned short f2bf(float f) {
    unsigned int u = __float_as_uint(f);
    u += 0x7fffu + ((u >> 16) & 1u);          // round-to-nearest-even
    return (unsigned short)(u >> 16);
}

__device__ __forceinline__ void load_lds_128(const unsigned short* g, unsigned short* l) {
    __builtin_amdgcn_global_load_lds(
        (const __attribute__((address_space(1))) void*)g,
        (__attribute__((address_space(3))) void*)l, 16, 0, 0);
}

// ---------------------------------------------------------------------------
// NT GEMM, bf16 MFMA 32x32x16, 128x128 block, BK=64, 4 waves (2x2 of 64x64).
// R4-proven core: rotate-by-row 16B-chunk swizzle (structural-min conflicts),
// 2-barrier K-loop. New in R6: XCD-aware 1D-grid decode per MODE (pins the
// small operand in one XCD's L2 to cut load latency = the measured drain).
// MODE 0: fused QKV epilogue (q,k bf16 + bias; v transposed into vt + bias)
//         grid 1536 = 8 xcd x (64 m x 3 n)
// MODE 2: bf16 P = exp(acc*alpha) + fused rowsum atomicAdd into rs
//         grid 1024 = 8 xcd x (2 n x 4 z x 16 m)
// MODE 1: fp32 C = acc / rs[row]  (normalized P.V)
//         grid  512 = 8 xcd x (1 n x 4 z x 16 m)
// ---------------------------------------------------------------------------
template <int MODE>
__global__ __launch_bounds__(256)
void gemm_bt(const unsigned short* __restrict__ A, const unsigned short* __restrict__ B,
             void* __restrict__ Cv,
             const float* __restrict__ b0, const float* __restrict__ b1,
             const float* __restrict__ b2, unsigned short* __restrict__ vt,
             float* __restrict__ rs,
             int K, int lda, int ldb, int ldc,
             long sA, long sB, long sC, float alpha)
{
    __shared__ unsigned short As[128 * BK];   // 16 KB
    __shared__ unsigned short Bs[128 * BK];   // 16 KB

    const int tid  = threadIdx.x;
    const int wave = tid >> 6;
    const int lane = tid & 63;
    const int l31  = lane & 31;
    const int half = lane >> 5;

    // ---- XCD-aware block decode (consecutive ids round-robin XCDs: id&7) --
    int mt, nt, z;
    {
        const int id  = blockIdx.x;
        const int xcd = id & 7;
        const int c   = id >> 3;
        if (MODE == 0) {            // 64 m-tiles x 24 n-tiles; 3 n per XCD
            mt = c & 63;  nt = xcd * 3 + (c >> 6);          z = 0;
        } else if (MODE == 2) {     // 16 m x 16 n x 4 z; 2 n per XCD
            nt = xcd * 2 + (c & 1); z = (c >> 1) & 3;       mt = c >> 3;
        } else {                    // 16 m x 8 n x 4 z; 1 n per XCD
            nt = xcd;               z = c & 3;              mt = c >> 2;
        }
    }
    const int m0 = mt * 128;
    const int n0 = nt * 128;
    A += (long)z * sA;
    B += (long)z * sB;

    const int wm = (wave >> 1) * 64;
    const int wn = (wave & 1) * 64;

    f32x16 acc[2][2] = {};

    // ---- staging map: chunk ch = tid + 256p -> row ch>>3, slot ch&7 ----
    // row r_p = (tid>>3) + 32p; slot c = tid&7; global chunk g = (c - r) & 7
    const int r0 = tid >> 3;
    const int g  = ((tid & 7) - r0) & 7;
    const unsigned short* Ag = A + (long)(m0 + r0) * lda + g * 8;
    const unsigned short* Bg = B + (long)(n0 + r0) * ldb + g * 8;
    unsigned short* Al = As + tid * 8;
    unsigned short* Bl = Bs + tid * 8;

    // ---- fragment LDS offsets (lane-constant), un-rotated ----
    const unsigned short* Af[2][4];
    const unsigned short* Bf[2][4];
#pragma unroll
    for (int i = 0; i < 2; ++i) {
        const int rrA = wm + i * 32 + l31;
        const int rrB = wn + i * 32 + l31;
#pragma unroll
        for (int h = 0; h < 4; ++h) {
            const int gw = h * 2 + half;
            Af[i][h] = As + rrA * BK + (((gw + rrA) & 7) << 3);
            Bf[i][h] = Bs + rrB * BK + (((gw + rrB) & 7) << 3);
        }
    }

    for (int k0 = 0; k0 < K; k0 += BK) {
#pragma unroll
        for (int p = 0; p < 4; ++p) {
            load_lds_128(Ag + k0 + (long)(32 * p) * lda, Al + 2048 * p);
            load_lds_128(Bg + k0 + (long)(32 * p) * ldb, Bl + 2048 * p);
        }
        __syncthreads();                       // vmcnt(0) drain + barrier
        bf16x8 a[2][4], b[2][4];
#pragma unroll
        for (int i = 0; i < 2; ++i)
#pragma unroll
            for (int h = 0; h < 4; ++h) {
                a[i][h] = *(const bf16x8*)Af[i][h];
                b[i][h] = *(const bf16x8*)Bf[i][h];
            }
#pragma unroll
        for (int h = 0; h < 4; ++h)
#pragma unroll
            for (int i = 0; i < 2; ++i)
#pragma unroll
                for (int j = 0; j < 2; ++j)
                    acc[i][j] = __builtin_amdgcn_mfma_f32_32x32x16_bf16(
                        a[i][h], b[j][h], acc[i][j], 0, 0, 0);
        __syncthreads();
    }

    // C/D: col = lane&31, row = (reg&3) + 8*(reg>>2) + 4*(lane>>5)  [m74/m101]
    if (MODE == 0) {
        if (n0 >= 2048) {
            // V columns -> vt[b][d][m] (+bias), packed 4-m ushort4 stores
#pragma unroll
            for (int j = 0; j < 2; ++j) {
                const int d = n0 - 2048 + wn + j * 32 + l31;
                const float bias = b2[d];
#pragma unroll
                for (int i = 0; i < 2; ++i) {
                    const int mbase = m0 + wm + i * 32 + 4 * half;
#pragma unroll
                    for (int rq = 0; rq < 4; ++rq) {
                        const int rowi = mbase + 8 * rq;
                        const int bb = rowi >> 11;
                        const int mm = rowi & 2047;
                        ushort4 u;
                        u.x = f2bf(acc[i][j][rq * 4 + 0] + bias);
                        u.y = f2bf(acc[i][j][rq * 4 + 1] + bias);
                        u.z = f2bf(acc[i][j][rq * 4 + 2] + bias);
                        u.w = f2bf(acc[i][j][rq * 4 + 3] + bias);
                        *(ushort4*)(vt + ((long)bb * DIM + d) * SEQ + mm) = u;
                    }
                }
            }
        } else {
            unsigned short* C16 = (unsigned short*)Cv;
#pragma unroll
            for (int j = 0; j < 2; ++j) {
                const int col = n0 + wn + j * 32 + l31;
                const float* bp = (col >> 10) ? b1 : b0;
                const float bias = bp[col & 1023];
#pragma unroll
                for (int i = 0; i < 2; ++i)
#pragma unroll
                    for (int r = 0; r < 16; ++r) {
                        const int rowi = m0 + wm + i * 32 + (r & 3) + 8 * (r >> 2) + 4 * half;
                        C16[(long)rowi * ldc + col] = f2bf(acc[i][j][r] + bias);
                    }
            }
        }
    } else if (MODE == 2) {
        // P = exp(acc*alpha) bf16 + fused rowsum (shfl over 32 col-lanes)
        unsigned short* C16 = (unsigned short*)Cv + (long)z * sC;
        float* rsz = rs + (long)z * SEQ;
#pragma unroll
        for (int i = 0; i < 2; ++i)
#pragma unroll
            for (int r = 0; r < 16; ++r) {
                const int rowi = m0 + wm + i * 32 + (r & 3) + 8 * (r >> 2) + 4 * half;
                const float p0 = __expf(acc[i][0][r] * alpha);
                const float p1 = __expf(acc[i][1][r] * alpha);
                C16[(long)rowi * ldc + n0 + wn + l31]      = f2bf(p0);
                C16[(long)rowi * ldc + n0 + wn + 32 + l31] = f2bf(p1);
                float v = p0 + p1;
                v += __shfl_xor(v, 1);  v += __shfl_xor(v, 2);
                v += __shfl_xor(v, 4);  v += __shfl_xor(v, 8);
                v += __shfl_xor(v, 16);
                if (l31 == 0) atomicAdd(rsz + rowi, v);
            }
    } else {  // MODE 1: C = acc / rs[row]
        float* C = (float*)Cv + (long)z * sC;
        const float* rsz = rs + (long)z * SEQ;
#pragma unroll
        for (int i = 0; i < 2; ++i) {
            const int rbase = m0 + wm + i * 32 + 4 * half;
#pragma unroll
            for (int rq = 0; rq < 4; ++rq) {
                const float4 s4 = *(const float4*)(rsz + rbase + 8 * rq);
                float4 inv4;
                inv4.x = 1.0f / s4.x; inv4.y = 1.0f / s4.y;
                inv4.z = 1.0f / s4.z; inv4.w = 1.0f / s4.w;
#pragma unroll
                for (int j = 0; j < 2; ++j) {
                    const int col = n0 + wn + j * 32 + l31;
                    C[(long)(rbase + 8 * rq + 0) * ldc + col] = acc[i][j][rq * 4 + 0] * inv4.x;
                    C[(long)(rbase + 8 * rq + 1) * ldc + col] = acc[i][j][rq * 4 + 1] * inv4.y;
                    C[(long)(rbase + 8 * rq + 2) * ldc + col] = acc[i][j][rq * 4 + 2] * inv4.z;
                    C[(long)(rbase + 8 * rq + 3) * ldc + col] = acc[i][j][rq * 4 + 3] * inv4.w;
                }
            }
        }
    }
}

// ---------------------------------------------------------------------------
// Single launch: convert x (8192x1024) and Wq|Wk|Wv (each 1024x1024) to bf16.
// ---------------------------------------------------------------------------
__global__ __launch_bounds__(256)
void cvt_all(const float* __restrict__ x, const float* __restrict__ Wq,
             const float* __restrict__ Wk, const float* __restrict__ Wv,
             unsigned short* __restrict__ xb, unsigned short* __restrict__ Wb)
{
    const long NX = (long)NTOK * DIM / 4;     // 2M float4 groups
    const long NW = (long)DIM * DIM / 4;      // 256K
    long i = (long)blockIdx.x * 256 + threadIdx.x;
    const float* src;
    unsigned short* dst;
    long j;
    if (i < NX)               { src = x;  dst = xb;                 j = i; }
    else if (i < NX + NW)     { src = Wq; dst = Wb;                 j = i - NX; }
    else if (i < NX + 2 * NW) { src = Wk; dst = Wb + DIM * DIM;     j = i - NX - NW; }
    else                      { src = Wv; dst = Wb + 2 * DIM * DIM; j = i - NX - 2 * NW; }
    float4 f = ((const float4*)src)[j];
    ushort4 u;
    u.x = f2bf(f.x); u.y = f2bf(f.y); u.z = f2bf(f.z); u.w = f2bf(f.w);
    ((ushort4*)dst)[j] = u;
}

// ---------------------------------------------------------------------------
extern "C" void kernel_launch(void* const* d_in, const int* in_sizes, int n_in,
                              void* d_out, int out_size, void* d_ws, size_t ws_size,
                              hipStream_t stream)
{
    const float* x  = (const float*)d_in[0];
    const float* Wq = (const float*)d_in[1];
    const float* bq = (const float*)d_in[2];
    const float* Wk = (const float*)d_in[3];
    const float* bk = (const float*)d_in[4];
    const float* Wv = (const float*)d_in[5];
    const float* bv = (const float*)d_in[6];
    float* out = (float*)d_out;

    // Workspace (>=167.8MB proven R1):
    //  [0,16MB):    xb bf16 [8192][1024]
    //  [16,22MB):   Wb bf16 [3][1024][1024]
    //  [64,112MB):  qkv bf16 [8192][3072]  (V cols never written; vt instead)
    //  [112,128MB): vt  bf16 [4][1024][2048]
    //  [128,160MB): P   bf16 [4][2048][2048]  (unnormalized exp)
    //  [160MB,+32KB): rs fp32 [4][2048] (atomic rowsums)
    char* ws = (char*)d_ws;
    unsigned short* xb   = (unsigned short*)ws;
    unsigned short* Wb   = (unsigned short*)(ws + 16u * 1024 * 1024);
    unsigned short* qkv  = (unsigned short*)(ws + 64u * 1024 * 1024);
    unsigned short* vt   = (unsigned short*)(ws + 112u * 1024 * 1024);
    unsigned short* P    = (unsigned short*)(ws + 128u * 1024 * 1024);
    float*          rs   = (float*)(ws + 160u * 1024 * 1024);

    const float scale = 0.03125f;   // 1/sqrt(1024)
    dim3 blk(256);

    // 1) converts (single launch) + zero the atomic rowsum buffer
    cvt_all<<<(NTOK * DIM / 4 + 3 * DIM * DIM / 4) / 256, blk, 0, stream>>>(
        x, Wq, Wk, Wv, xb, Wb);
    hipMemsetAsync(rs, 0, 4 * SEQ * sizeof(float), stream);

    // 2) fused QKV projection (V transposed into vt in-epilogue)
    gemm_bt<0><<<1536, blk, 0, stream>>>(
        xb, Wb, qkv, bq, bk, bv, vt, nullptr,
        DIM, DIM, DIM, NQKV, 0, 0, 0, 1.0f);

    // 3) P[b] = exp(q[b] . k[b]^T * scale)  bf16, + fused rowsum atomics
    gemm_bt<2><<<1024, blk, 0, stream>>>(
        qkv, qkv + 1024, P, nullptr, nullptr, nullptr, nullptr, rs,
        DIM, NQKV, NQKV, SEQ,
        (long)SEQ * NQKV, (long)SEQ * NQKV, (long)SEQ * SEQ, scale);

    // 4) out[b] = (P[b] . vt[b]^T) / rs  (fp32)
    gemm_bt<1><<<512, blk, 0, stream>>>(
        P, vt, out, nullptr, nullptr, nullptr, nullptr, rs,
        SEQ, SEQ, SEQ, DIM,
        (long)SEQ * SEQ, (long)DIM * SEQ, (long)SEQ * DIM, 1.0f);
}

// Round 7
// 275.494 us; speedup vs baseline: 1.0860x; 1.0379x over previous
//
#include <hip/hip_runtime.h>

#define SEQ  2048
#define DIM  1024
#define NTOK 8192   // 4*SEQ
#define NQKV 3072
#define BK   64

typedef __attribute__((ext_vector_type(8)))  __bf16 bf16x8;
typedef __attribute__((ext_vector_type(16))) float  f32x16;

__device__ __forceinline__ unsigned short f2bf(float f) {
    unsigned int u = __float_as_uint(f);
    u += 0x7fffu + ((u >> 16) & 1u);          // round-to-nearest-even
    return (unsigned short)(u >> 16);
}

__device__ __forceinline__ void load_lds_128(const unsigned short* g, unsigned short* l) {
    __builtin_amdgcn_global_load_lds(
        (const __attribute__((address_space(1))) void*)g,
        (__attribute__((address_space(3))) void*)l, 16, 0, 0);
}

// ---------------------------------------------------------------------------
// NT GEMM, bf16 MFMA 32x32x16, 128x128 block, BK=64, 4 waves (2x2 of 64x64).
// R4-proven core: rotate-by-row 16B-chunk swizzle (conflicts at structural
// 8-wrap minimum), 2-barrier K-loop, plain 3D grid (blockIdx.x = m-tile
// fastest -> round-robin XCD dispatch shares the small per-n-tile operand
// within each XCD L2 while the large operand is fetched ~once; R6's manual
// XCD pinning inverted this and 4x'd FETCH_SIZE).
// MODE 0: fused QKV epilogue (q,k bf16 + bias; v transposed into vt + bias)
// MODE 2: bf16 P = exp(acc*alpha) + fused rowsum atomicAdd into rs
// MODE 1: fp32 C = acc / rs[row]  (normalized P.V)
// ---------------------------------------------------------------------------
template <int MODE>
__global__ __launch_bounds__(256)
void gemm_bt(const unsigned short* __restrict__ A, const unsigned short* __restrict__ B,
             void* __restrict__ Cv,
             const float* __restrict__ b0, const float* __restrict__ b1,
             const float* __restrict__ b2, unsigned short* __restrict__ vt,
             float* __restrict__ rs,
             int K, int lda, int ldb, int ldc,
             long sA, long sB, long sC, float alpha)
{
    __shared__ unsigned short As[128 * BK];   // 16 KB
    __shared__ unsigned short Bs[128 * BK];   // 16 KB

    const int tid  = threadIdx.x;
    const int wave = tid >> 6;
    const int lane = tid & 63;
    const int l31  = lane & 31;
    const int half = lane >> 5;

    const int m0 = blockIdx.x * 128;
    const int n0 = blockIdx.y * 128;
    const int z  = blockIdx.z;
    A += (long)z * sA;
    B += (long)z * sB;

    const int wm = (wave >> 1) * 64;
    const int wn = (wave & 1) * 64;

    f32x16 acc[2][2] = {};

    // ---- staging map: chunk ch = tid + 256p -> row ch>>3, slot ch&7 ----
    // row r_p = (tid>>3) + 32p; slot c = tid&7; global chunk g = (c - r) & 7
    const int r0 = tid >> 3;
    const int g  = ((tid & 7) - r0) & 7;
    const unsigned short* Ag = A + (long)(m0 + r0) * lda + g * 8;
    const unsigned short* Bg = B + (long)(n0 + r0) * ldb + g * 8;
    unsigned short* Al = As + tid * 8;
    unsigned short* Bl = Bs + tid * 8;

    // ---- fragment LDS offsets (lane-constant), un-rotated ----
    const unsigned short* Af[2][4];
    const unsigned short* Bf[2][4];
#pragma unroll
    for (int i = 0; i < 2; ++i) {
        const int rrA = wm + i * 32 + l31;
        const int rrB = wn + i * 32 + l31;
#pragma unroll
        for (int h = 0; h < 4; ++h) {
            const int gw = h * 2 + half;
            Af[i][h] = As + rrA * BK + (((gw + rrA) & 7) << 3);
            Bf[i][h] = Bs + rrB * BK + (((gw + rrB) & 7) << 3);
        }
    }

    for (int k0 = 0; k0 < K; k0 += BK) {
#pragma unroll
        for (int p = 0; p < 4; ++p) {
            load_lds_128(Ag + k0 + (long)(32 * p) * lda, Al + 2048 * p);
            load_lds_128(Bg + k0 + (long)(32 * p) * ldb, Bl + 2048 * p);
        }
        __syncthreads();                       // vmcnt(0) drain + barrier
        bf16x8 a[2][4], b[2][4];
#pragma unroll
        for (int i = 0; i < 2; ++i)
#pragma unroll
            for (int h = 0; h < 4; ++h) {
                a[i][h] = *(const bf16x8*)Af[i][h];
                b[i][h] = *(const bf16x8*)Bf[i][h];
            }
#pragma unroll
        for (int h = 0; h < 4; ++h)
#pragma unroll
            for (int i = 0; i < 2; ++i)
#pragma unroll
                for (int j = 0; j < 2; ++j)
                    acc[i][j] = __builtin_amdgcn_mfma_f32_32x32x16_bf16(
                        a[i][h], b[j][h], acc[i][j], 0, 0, 0);
        __syncthreads();
    }

    // C/D: col = lane&31, row = (reg&3) + 8*(reg>>2) + 4*(lane>>5)  [m74/m101]
    if (MODE == 0) {
        if (n0 >= 2048) {
            // V columns -> vt[b][d][m] (+bias), packed 4-m ushort4 stores
#pragma unroll
            for (int j = 0; j < 2; ++j) {
                const int d = n0 - 2048 + wn + j * 32 + l31;
                const float bias = b2[d];
#pragma unroll
                for (int i = 0; i < 2; ++i) {
                    const int mbase = m0 + wm + i * 32 + 4 * half;
#pragma unroll
                    for (int rq = 0; rq < 4; ++rq) {
                        const int rowi = mbase + 8 * rq;
                        const int bb = rowi >> 11;
                        const int mm = rowi & 2047;
                        ushort4 u;
                        u.x = f2bf(acc[i][j][rq * 4 + 0] + bias);
                        u.y = f2bf(acc[i][j][rq * 4 + 1] + bias);
                        u.z = f2bf(acc[i][j][rq * 4 + 2] + bias);
                        u.w = f2bf(acc[i][j][rq * 4 + 3] + bias);
                        *(ushort4*)(vt + ((long)bb * DIM + d) * SEQ + mm) = u;
                    }
                }
            }
        } else {
            unsigned short* C16 = (unsigned short*)Cv;
#pragma unroll
            for (int j = 0; j < 2; ++j) {
                const int col = n0 + wn + j * 32 + l31;
                const float* bp = (col >> 10) ? b1 : b0;
                const float bias = bp[col & 1023];
#pragma unroll
                for (int i = 0; i < 2; ++i)
#pragma unroll
                    for (int r = 0; r < 16; ++r) {
                        const int rowi = m0 + wm + i * 32 + (r & 3) + 8 * (r >> 2) + 4 * half;
                        C16[(long)rowi * ldc + col] = f2bf(acc[i][j][r] + bias);
                    }
            }
        }
    } else if (MODE == 2) {
        // P = exp(acc*alpha) bf16 + fused rowsum (shfl over 32 col-lanes)
        unsigned short* C16 = (unsigned short*)Cv + (long)z * sC;
        float* rsz = rs + (long)z * SEQ;
#pragma unroll
        for (int i = 0; i < 2; ++i)
#pragma unroll
            for (int r = 0; r < 16; ++r) {
                const int rowi = m0 + wm + i * 32 + (r & 3) + 8 * (r >> 2) + 4 * half;
                const float p0 = __expf(acc[i][0][r] * alpha);
                const float p1 = __expf(acc[i][1][r] * alpha);
                C16[(long)rowi * ldc + n0 + wn + l31]      = f2bf(p0);
                C16[(long)rowi * ldc + n0 + wn + 32 + l31] = f2bf(p1);
                float v = p0 + p1;
                v += __shfl_xor(v, 1);  v += __shfl_xor(v, 2);
                v += __shfl_xor(v, 4);  v += __shfl_xor(v, 8);
                v += __shfl_xor(v, 16);
                if (l31 == 0) atomicAdd(rsz + rowi, v);
            }
    } else {  // MODE 1: C = acc / rs[row]
        float* C = (float*)Cv + (long)z * sC;
        const float* rsz = rs + (long)z * SEQ;
#pragma unroll
        for (int i = 0; i < 2; ++i) {
            const int rbase = m0 + wm + i * 32 + 4 * half;
#pragma unroll
            for (int rq = 0; rq < 4; ++rq) {
                const float4 s4 = *(const float4*)(rsz + rbase + 8 * rq);
                float4 inv4;
                inv4.x = 1.0f / s4.x; inv4.y = 1.0f / s4.y;
                inv4.z = 1.0f / s4.z; inv4.w = 1.0f / s4.w;
#pragma unroll
                for (int j = 0; j < 2; ++j) {
                    const int col = n0 + wn + j * 32 + l31;
                    C[(long)(rbase + 8 * rq + 0) * ldc + col] = acc[i][j][rq * 4 + 0] * inv4.x;
                    C[(long)(rbase + 8 * rq + 1) * ldc + col] = acc[i][j][rq * 4 + 1] * inv4.y;
                    C[(long)(rbase + 8 * rq + 2) * ldc + col] = acc[i][j][rq * 4 + 2] * inv4.z;
                    C[(long)(rbase + 8 * rq + 3) * ldc + col] = acc[i][j][rq * 4 + 3] * inv4.w;
                }
            }
        }
    }
}

// ---------------------------------------------------------------------------
// Single launch: convert x (8192x1024) and Wq|Wk|Wv (each 1024x1024) to bf16.
// ---------------------------------------------------------------------------
__global__ __launch_bounds__(256)
void cvt_all(const float* __restrict__ x, const float* __restrict__ Wq,
             const float* __restrict__ Wk, const float* __restrict__ Wv,
             unsigned short* __restrict__ xb, unsigned short* __restrict__ Wb)
{
    const long NX = (long)NTOK * DIM / 4;     // 2M float4 groups
    const long NW = (long)DIM * DIM / 4;      // 256K
    long i = (long)blockIdx.x * 256 + threadIdx.x;
    const float* src;
    unsigned short* dst;
    long j;
    if (i < NX)               { src = x;  dst = xb;                 j = i; }
    else if (i < NX + NW)     { src = Wq; dst = Wb;                 j = i - NX; }
    else if (i < NX + 2 * NW) { src = Wk; dst = Wb + DIM * DIM;     j = i - NX - NW; }
    else                      { src = Wv; dst = Wb + 2 * DIM * DIM; j = i - NX - 2 * NW; }
    float4 f = ((const float4*)src)[j];
    ushort4 u;
    u.x = f2bf(f.x); u.y = f2bf(f.y); u.z = f2bf(f.z); u.w = f2bf(f.w);
    ((ushort4*)dst)[j] = u;
}

// ---------------------------------------------------------------------------
extern "C" void kernel_launch(void* const* d_in, const int* in_sizes, int n_in,
                              void* d_out, int out_size, void* d_ws, size_t ws_size,
                              hipStream_t stream)
{
    const float* x  = (const float*)d_in[0];
    const float* Wq = (const float*)d_in[1];
    const float* bq = (const float*)d_in[2];
    const float* Wk = (const float*)d_in[3];
    const float* bk = (const float*)d_in[4];
    const float* Wv = (const float*)d_in[5];
    const float* bv = (const float*)d_in[6];
    float* out = (float*)d_out;

    // Workspace (>=167.8MB proven R1):
    //  [0,16MB):    xb bf16 [8192][1024]
    //  [16,22MB):   Wb bf16 [3][1024][1024]
    //  [64,112MB):  qkv bf16 [8192][3072]  (V cols never written; vt instead)
    //  [112,128MB): vt  bf16 [4][1024][2048]
    //  [128,160MB): P   bf16 [4][2048][2048]  (unnormalized exp)
    //  [160MB,+32KB): rs fp32 [4][2048] (atomic rowsums)
    char* ws = (char*)d_ws;
    unsigned short* xb   = (unsigned short*)ws;
    unsigned short* Wb   = (unsigned short*)(ws + 16u * 1024 * 1024);
    unsigned short* qkv  = (unsigned short*)(ws + 64u * 1024 * 1024);
    unsigned short* vt   = (unsigned short*)(ws + 112u * 1024 * 1024);
    unsigned short* P    = (unsigned short*)(ws + 128u * 1024 * 1024);
    float*          rs   = (float*)(ws + 160u * 1024 * 1024);

    const float scale = 0.03125f;   // 1/sqrt(1024)
    dim3 blk(256);

    // 1) converts (single launch) + zero the atomic rowsum buffer
    cvt_all<<<(NTOK * DIM / 4 + 3 * DIM * DIM / 4) / 256, blk, 0, stream>>>(
        x, Wq, Wk, Wv, xb, Wb);
    hipMemsetAsync(rs, 0, 4 * SEQ * sizeof(float), stream);

    // 2) fused QKV projection (V transposed into vt in-epilogue)
    gemm_bt<0><<<dim3(NTOK / 128, NQKV / 128), blk, 0, stream>>>(
        xb, Wb, qkv, bq, bk, bv, vt, nullptr,
        DIM, DIM, DIM, NQKV, 0, 0, 0, 1.0f);

    // 3) P[b] = exp(q[b] . k[b]^T * scale)  bf16, + fused rowsum atomics
    gemm_bt<2><<<dim3(SEQ / 128, SEQ / 128, 4), blk, 0, stream>>>(
        qkv, qkv + 1024, P, nullptr, nullptr, nullptr, nullptr, rs,
        DIM, NQKV, NQKV, SEQ,
        (long)SEQ * NQKV, (long)SEQ * NQKV, (long)SEQ * SEQ, scale);

    // 4) out[b] = (P[b] . vt[b]^T) / rs  (fp32)
    gemm_bt<1><<<dim3(SEQ / 128, DIM / 128, 4), blk, 0, stream>>>(
        P, vt, out, nullptr, nullptr, nullptr, nullptr, rs,
        SEQ, SEQ, SEQ, DIM,
        (long)SEQ * SEQ, (long)DIM * SEQ, (long)SEQ * DIM, 1.0f);
}